// Round 1
// baseline (4800.334 us; speedup 1.0000x reference)
//
#include <hip/hip_runtime.h>
#include <hip/hip_bf16.h>
#include <math.h>

// Problem constants
constexpr int B_ = 8;
constexpr int L_ = 2048;
constexpr int S_ = 1000;
constexpr int D_ = 1024;
constexpr int H_ = 8;
constexpr int E_ = 128;     // D/H
constexpr int TOPK_ = 10;
constexpr float SCALE_ = 0.08838834764831845f;  // 1/sqrt(E)

// Fused-scores kernel tiling
constexpr int NCH_ = 8;             // l-chunks per (b,h)
constexpr int CHR_ = L_ / NCH_;     // 256 rows per chunk
constexpr int TL_  = 32;            // rows per macro-tile

// ---------------------------------------------------------------------------
// Generic f32 GEMM + bias: C[M][N] = A[M][K] @ Bm[K][N] + bias[N]
// BM=BN=64, BK=16, 256 threads, 4x4 micro-tile per thread.
// ---------------------------------------------------------------------------
__global__ __launch_bounds__(256) void gemm_bias_kernel(
    const float* __restrict__ A, const float* __restrict__ Bm,
    const float* __restrict__ bias, float* __restrict__ C,
    int M, int N, int Kd)
{
    __shared__ float As[16][65];   // [BK][BM+1], A stored transposed
    __shared__ float Bs[16][68];   // [BK][BN+4]

    const int t  = threadIdx.x;
    const int tx = t & 15;
    const int ty = t >> 4;
    const int m0 = blockIdx.y * 64;
    const int n0 = blockIdx.x * 64;

    float acc[4][4];
#pragma unroll
    for (int i = 0; i < 4; ++i)
#pragma unroll
        for (int j = 0; j < 4; ++j) acc[i][j] = 0.f;

    for (int k0 = 0; k0 < Kd; k0 += 16) {
        // stage A tile (64 x 16), transposed into As
        {
            const int row = t >> 2;            // 0..63
            const int c4  = (t & 3) * 4;       // 0..12
            float4 v = {0.f, 0.f, 0.f, 0.f};
            if (m0 + row < M)
                v = *(const float4*)&A[(size_t)(m0 + row) * Kd + k0 + c4];
            As[c4 + 0][row] = v.x;
            As[c4 + 1][row] = v.y;
            As[c4 + 2][row] = v.z;
            As[c4 + 3][row] = v.w;
        }
        // stage B tile (16 x 64)
        {
            const int row = t >> 4;            // 0..15
            const int c4  = (t & 15) * 4;      // 0..60
            float4 v = *(const float4*)&Bm[(size_t)(k0 + row) * N + n0 + c4];
            *(float4*)&Bs[row][c4] = v;
        }
        __syncthreads();
#pragma unroll
        for (int k = 0; k < 16; ++k) {
            float a[4], b[4];
#pragma unroll
            for (int i = 0; i < 4; ++i) a[i] = As[k][ty * 4 + i];
            float4 bv = *(const float4*)&Bs[k][tx * 4];
            b[0] = bv.x; b[1] = bv.y; b[2] = bv.z; b[3] = bv.w;
#pragma unroll
            for (int i = 0; i < 4; ++i)
#pragma unroll
                for (int j = 0; j < 4; ++j) acc[i][j] += a[i] * b[j];
        }
        __syncthreads();
    }

#pragma unroll
    for (int i = 0; i < 4; ++i) {
        const int row = m0 + ty * 4 + i;
        if (row < M) {
#pragma unroll
            for (int j = 0; j < 4; ++j) {
                const int col = n0 + tx * 4 + j;
                C[(size_t)row * N + col] = acc[i][j] + bias[col];
            }
        }
    }
}

// ---------------------------------------------------------------------------
// Fused Q-proj + scores + softmax + tmps accumulation.
// Grid: B*H*NCH blocks of 256 threads. Each block: one (b,h), 256 l-rows.
// Per 32-row macro-tile: Phase A computes q (scaled) into LDS;
// Phase B: two 16-row sub-passes; each wave owns 4 rows, lane owns
// s = lane + 64*st (16 score regs per row) -- flash-style register rows.
// ---------------------------------------------------------------------------
__global__ __launch_bounds__(256) void scores_kernel(
    const float* __restrict__ tgt, const float* __restrict__ Wq,
    const float* __restrict__ bq,  const float* __restrict__ K,
    float* __restrict__ tmps)
{
    const int t     = threadIdx.x;
    const int blk   = blockIdx.x;
    const int chunk = blk & (NCH_ - 1);
    const int h     = (blk >> 3) & (H_ - 1);
    const int b     = blk >> 6;
    const int l0    = chunk * CHR_;
    const int lane  = t & 63;
    const int wave  = t >> 6;

    __shared__ float q_s[TL_ * 132];     // 32 rows x 128 (pad to 132)
    __shared__ float tmps_l[S_];
    __shared__ float stage[8192];        // union: Ksh[64][128] | {tgt_s[32][33], wq_s[32][132]}
    float* tgt_s = stage;                // 32*33 = 1056
    float* wq_s  = stage + 1056;         // 32*132 = 4224

    for (int i = t; i < S_; i += 256) tmps_l[i] = 0.f;
    __syncthreads();

    const int rr = t >> 4;   // 0..15 (phase A rows rr, rr+16)
    const int ec = t & 15;   // phase A col group: e = ec + 16*j

    for (int mt = 0; mt < CHR_ / TL_; ++mt) {
        const int lrow0 = l0 + mt * TL_;

        // ---------------- Phase A: q-projection (32 rows x 128 cols) -------
        float acc0[8], acc1[8];
#pragma unroll
        for (int j = 0; j < 8; ++j) { acc0[j] = 0.f; acc1[j] = 0.f; }

        for (int k0 = 0; k0 < D_; k0 += 32) {
            {   // stage target tile 32x32
                const int row = t >> 3;          // 0..31
                const int c4  = (t & 7) * 4;     // 0..28
                float4 v = *(const float4*)&tgt[((size_t)(b * L_ + lrow0 + row)) * D_ + k0 + c4];
                tgt_s[row * 33 + c4 + 0] = v.x;
                tgt_s[row * 33 + c4 + 1] = v.y;
                tgt_s[row * 33 + c4 + 2] = v.z;
                tgt_s[row * 33 + c4 + 3] = v.w;
            }
#pragma unroll
            for (int kq = 0; kq < 4; ++kq) {     // stage Wq tile 32x128
                const int id  = kq * 256 + t;
                const int row = id >> 5;         // 0..31
                const int c4  = (id & 31) * 4;   // 0..124
                float4 v = *(const float4*)&Wq[(size_t)(k0 + row) * D_ + h * E_ + c4];
                *(float4*)&wq_s[row * 132 + c4] = v;
            }
            __syncthreads();
#pragma unroll
            for (int kk = 0; kk < 32; ++kk) {
                const float a0 = tgt_s[rr * 33 + kk];
                const float a1 = tgt_s[(rr + 16) * 33 + kk];
#pragma unroll
                for (int j = 0; j < 8; ++j) {
                    const float w = wq_s[kk * 132 + ec + 16 * j];
                    acc0[j] += a0 * w;
                    acc1[j] += a1 * w;
                }
            }
            __syncthreads();
        }
        // write q (scaled) into LDS
#pragma unroll
        for (int j = 0; j < 8; ++j) {
            const float bqv = bq[h * E_ + ec + 16 * j];
            q_s[rr * 132 + ec + 16 * j]        = (acc0[j] + bqv) * SCALE_;
            q_s[(rr + 16) * 132 + ec + 16 * j] = (acc1[j] + bqv) * SCALE_;
        }
        __syncthreads();

        // ---------------- Phase B: scores + softmax + tmps -----------------
        for (int sp = 0; sp < 2; ++sp) {
            const int rbase = sp * 16 + wave * 4;   // wave's 4 rows in q_s

            float sc[4][16];
#pragma unroll
            for (int r = 0; r < 4; ++r)
#pragma unroll
                for (int st = 0; st < 16; ++st) sc[r][st] = 0.f;

#pragma unroll
            for (int st = 0; st < 16; ++st) {
                const int s0 = st * 64;
                // stage K tile (64 sources x 128 dims), XOR-swizzled
#pragma unroll
                for (int kq = 0; kq < 8; ++kq) {
                    const int id   = kq * 256 + t;
                    const int row  = id >> 5;        // 0..63
                    const int c4   = id & 31;        // f4 col 0..31
                    const int srow = s0 + row;
                    float4 v = {0.f, 0.f, 0.f, 0.f};
                    if (srow < S_)
                        v = *(const float4*)&K[(size_t)srow * D_ + h * E_ + c4 * 4];
                    const int slot = c4 ^ (row & 31);
                    *(float4*)&stage[row * 128 + slot * 4] = v;
                }
                __syncthreads();
                const int lx = lane & 31;
                for (int e4 = 0; e4 < 32; ++e4) {
                    const float4 kv = *(const float4*)&stage[lane * 128 + ((e4 ^ lx) << 2)];
#pragma unroll
                    for (int r = 0; r < 4; ++r) {
                        const float4 qv = *(const float4*)&q_s[(rbase + r) * 132 + (e4 << 2)];
                        sc[r][st] += qv.x * kv.x + qv.y * kv.y + qv.z * kv.z + qv.w * kv.w;
                    }
                }
                __syncthreads();
            }

            // mask invalid sources in last tile (s = 960 + lane >= 1000)
            constexpr int TAIL = S_ - 15 * 64;   // 40
            if (lane >= TAIL) {
#pragma unroll
                for (int r = 0; r < 4; ++r) sc[r][15] = -1e30f;
            }

            // per-row softmax (row fully resident in wave registers)
#pragma unroll
            for (int r = 0; r < 4; ++r) {
                float m = sc[r][0];
#pragma unroll
                for (int st = 1; st < 16; ++st) m = fmaxf(m, sc[r][st]);
#pragma unroll
                for (int off = 32; off > 0; off >>= 1) m = fmaxf(m, __shfl_xor(m, off));

                float p[16];
                float sum = 0.f;
#pragma unroll
                for (int st = 0; st < 16; ++st) {
                    p[st] = __expf(sc[r][st] - m);
                    sum += p[st];
                }
#pragma unroll
                for (int off = 32; off > 0; off >>= 1) sum += __shfl_xor(sum, off);
                const float inv = 1.f / sum;

#pragma unroll
                for (int st = 0; st < 16; ++st) {
                    const int s = st * 64 + lane;
                    if (s < S_) atomicAdd(&tmps_l[s], p[st] * inv);
                }
            }
        }
        __syncthreads();
    }

    __syncthreads();
    for (int i = t; i < S_; i += 256)
        atomicAdd(&tmps[(size_t)(b * H_ + h) * S_ + i], tmps_l[i]);
}

// ---------------------------------------------------------------------------
// Top-k (k=10) per (b,h) over S=1000 values; ties -> smaller index (matches
// jax.lax.top_k). One block per (b,h).
// ---------------------------------------------------------------------------
__global__ __launch_bounds__(256) void topk_kernel(
    const float* __restrict__ tmps, int* __restrict__ idxs)
{
    const int bh = blockIdx.x;
    const int t  = threadIdx.x;
    __shared__ float v[S_];
    __shared__ float rv[256];
    __shared__ int   ri[256];

    for (int i = t; i < S_; i += 256) v[i] = tmps[(size_t)bh * S_ + i];
    __syncthreads();

    for (int it = 0; it < TOPK_; ++it) {
        float best = -1e38f;
        int bi = 0x7fffffff;
        for (int s = t; s < S_; s += 256) {
            const float x = v[s];
            if (x > best) { best = x; bi = s; }
        }
        rv[t] = best; ri[t] = bi;
        __syncthreads();
        for (int k = 128; k > 0; k >>= 1) {
            if (t < k) {
                const float x = rv[t + k];
                const int  xi = ri[t + k];
                if (x > rv[t] || (x == rv[t] && xi < ri[t])) { rv[t] = x; ri[t] = xi; }
            }
            __syncthreads();
        }
        if (t == 0) {
            idxs[bh * TOPK_ + it] = ri[0];
            v[ri[0]] = -1e38f;
        }
        __syncthreads();
    }
}

// ---------------------------------------------------------------------------
// Gather selected K rows into tok[b][topk][D] (head-interleaved layout).
// ---------------------------------------------------------------------------
__global__ __launch_bounds__(256) void gather_kernel(
    const float* __restrict__ K, const int* __restrict__ idxs,
    float* __restrict__ tok)
{
    const int o = blockIdx.x * 256 + threadIdx.x;
    if (o >= B_ * TOPK_ * D_) return;
    const int d  = o & (D_ - 1);
    const int tt = (o >> 10) % TOPK_;
    const int b  = o / (D_ * TOPK_);
    const int h  = d >> 7;
    const int s  = idxs[(b * H_ + h) * TOPK_ + tt];
    tok[o] = K[(size_t)s * D_ + d];
}

// ---------------------------------------------------------------------------
extern "C" void kernel_launch(void* const* d_in, const int* in_sizes, int n_in,
                              void* d_out, int out_size, void* d_ws, size_t ws_size,
                              hipStream_t stream)
{
    const float* tgt = (const float*)d_in[0];
    const float* src = (const float*)d_in[1];
    const float* Wq  = (const float*)d_in[2];
    const float* bq  = (const float*)d_in[3];
    const float* Wk  = (const float*)d_in[4];
    const float* bk  = (const float*)d_in[5];
    const float* Wo  = (const float*)d_in[6];
    const float* bo  = (const float*)d_in[7];
    float* out = (float*)d_out;

    float* ws   = (float*)d_ws;
    float* Kbuf = ws;                       // 1,024,000 f32
    float* tmps = ws + 1024000;             //    64,000 f32
    int*   idxs = (int*)(ws + 1088000);     //       640 i32
    float* tok  = ws + 1088640;             //    81,920 f32

    hipMemsetAsync(tmps, 0, (size_t)B_ * H_ * S_ * sizeof(float), stream);

    // K = source @ Wk + bk   (1000 x 1024)
    {
        dim3 g(D_ / 64, (S_ + 63) / 64);
        gemm_bias_kernel<<<g, 256, 0, stream>>>(src, Wk, bk, Kbuf, S_, D_, D_);
    }

    // fused q-proj + scores + softmax + tmps
    scores_kernel<<<B_ * H_ * NCH_, 256, 0, stream>>>(tgt, Wq, bq, Kbuf, tmps);

    topk_kernel<<<B_ * H_, 256, 0, stream>>>(tmps, idxs);

    gather_kernel<<<(B_ * TOPK_ * D_ + 255) / 256, 256, 0, stream>>>(Kbuf, idxs, tok);

    // out = tok @ Wo + bo   (80 x 1024)
    {
        dim3 g(D_ / 64, (B_ * TOPK_ + 63) / 64);
        gemm_bias_kernel<<<g, 256, 0, stream>>>(tok, Wo, bo, out, B_ * TOPK_, D_, D_);
    }
}

// Round 2
// 591.776 us; speedup vs baseline: 8.1117x; 8.1117x over previous
//
#include <hip/hip_runtime.h>
#include <hip/hip_bf16.h>
#include <math.h>

// Problem constants
constexpr int B_ = 8;
constexpr int L_ = 2048;
constexpr int S_ = 1000;
constexpr int D_ = 1024;
constexpr int H_ = 8;
constexpr int E_ = 128;     // D/H
constexpr int TOPK_ = 10;
constexpr float SCALE_ = 0.08838834764831845f;  // 1/sqrt(E)

typedef __attribute__((ext_vector_type(8))) short short8;   // 8 x bf16 (4 VGPRs)
typedef __attribute__((ext_vector_type(4))) float f32x4;

__device__ inline unsigned short f2bf(float x) {            // RTN-even f32->bf16
    unsigned u = __float_as_uint(x);
    unsigned r = (u + 0x7fffu + ((u >> 16) & 1u)) >> 16;
    return (unsigned short)r;
}
__device__ inline float bf2f(unsigned short s) {
    return __uint_as_float(((unsigned)s) << 16);
}

// ---------------------------------------------------------------------------
// Generic f32 GEMM + bias (round-1, passing): C[M][N] = A[M][K] @ Bm[K][N] + b
// ---------------------------------------------------------------------------
__global__ __launch_bounds__(256) void gemm_bias_kernel(
    const float* __restrict__ A, const float* __restrict__ Bm,
    const float* __restrict__ bias, float* __restrict__ C,
    int M, int N, int Kd)
{
    __shared__ float As[16][65];
    __shared__ float Bs[16][68];

    const int t  = threadIdx.x;
    const int tx = t & 15;
    const int ty = t >> 4;
    const int m0 = blockIdx.y * 64;
    const int n0 = blockIdx.x * 64;

    float acc[4][4];
#pragma unroll
    for (int i = 0; i < 4; ++i)
#pragma unroll
        for (int j = 0; j < 4; ++j) acc[i][j] = 0.f;

    for (int k0 = 0; k0 < Kd; k0 += 16) {
        {
            const int row = t >> 2;
            const int c4  = (t & 3) * 4;
            float4 v = {0.f, 0.f, 0.f, 0.f};
            if (m0 + row < M)
                v = *(const float4*)&A[(size_t)(m0 + row) * Kd + k0 + c4];
            As[c4 + 0][row] = v.x;
            As[c4 + 1][row] = v.y;
            As[c4 + 2][row] = v.z;
            As[c4 + 3][row] = v.w;
        }
        {
            const int row = t >> 4;
            const int c4  = (t & 15) * 4;
            float4 v = *(const float4*)&Bm[(size_t)(k0 + row) * N + n0 + c4];
            *(float4*)&Bs[row][c4] = v;
        }
        __syncthreads();
#pragma unroll
        for (int k = 0; k < 16; ++k) {
            float a[4], b[4];
#pragma unroll
            for (int i = 0; i < 4; ++i) a[i] = As[k][ty * 4 + i];
            float4 bv = *(const float4*)&Bs[k][tx * 4];
            b[0] = bv.x; b[1] = bv.y; b[2] = bv.z; b[3] = bv.w;
#pragma unroll
            for (int i = 0; i < 4; ++i)
#pragma unroll
                for (int j = 0; j < 4; ++j) acc[i][j] += a[i] * b[j];
        }
        __syncthreads();
    }

#pragma unroll
    for (int i = 0; i < 4; ++i) {
        const int row = m0 + ty * 4 + i;
        if (row < M) {
#pragma unroll
            for (int j = 0; j < 4; ++j) {
                const int col = n0 + tx * 4 + j;
                C[(size_t)row * N + col] = acc[i][j] + bias[col];
            }
        }
    }
}

// ---------------------------------------------------------------------------
// WqT split: WqTh/WqTl[n][k] (bf16 hi/lo) = transpose(Wq[k][n]).
// ---------------------------------------------------------------------------
__global__ __launch_bounds__(256) void splitWqT_kernel(
    const float* __restrict__ Wq,
    unsigned short* __restrict__ WqTh, unsigned short* __restrict__ WqTl)
{
    __shared__ __attribute__((aligned(16))) float tile[64][68];
    const int t  = threadIdx.x;
    const int k0 = blockIdx.y * 64, n0 = blockIdx.x * 64;
#pragma unroll
    for (int it = 0; it < 4; ++it) {
        int id = it * 256 + t;
        int r = id >> 4, c = id & 15;
        *(float4*)&tile[r][c * 4] = *(const float4*)&Wq[(size_t)(k0 + r) * D_ + n0 + c * 4];
    }
    __syncthreads();
#pragma unroll
    for (int it = 0; it < 4; ++it) {
        int id = it * 256 + t;
        int n = id >> 4, c = id & 15;      // out row n, k-chunk of 4
        unsigned short hs[4], ls[4];
#pragma unroll
        for (int i = 0; i < 4; ++i) {
            float x = tile[c * 4 + i][n];
            hs[i] = f2bf(x);
            ls[i] = f2bf(x - bf2f(hs[i]));
        }
        size_t o = (size_t)(n0 + n) * D_ + k0 + c * 4;
        uint2 uh; uh.x = (unsigned)hs[0] | ((unsigned)hs[1] << 16);
                  uh.y = (unsigned)hs[2] | ((unsigned)hs[3] << 16);
        uint2 ul; ul.x = (unsigned)ls[0] | ((unsigned)ls[1] << 16);
                  ul.y = (unsigned)ls[2] | ((unsigned)ls[3] << 16);
        *(uint2*)&WqTh[o] = uh;
        *(uint2*)&WqTl[o] = ul;
    }
}

// ---------------------------------------------------------------------------
// K split: Kh/Kl[1024(pad)][1024] bf16; rows >= 1000 zeroed.
// ---------------------------------------------------------------------------
__global__ __launch_bounds__(256) void splitK_kernel(
    const float* __restrict__ Kbuf,
    unsigned short* __restrict__ Kh, unsigned short* __restrict__ Kl)
{
    int idx  = blockIdx.x * 256 + threadIdx.x;
    int base = idx * 4;
    int row  = base >> 10;
    float4 v = {0.f, 0.f, 0.f, 0.f};
    if (row < S_) v = *(const float4*)&Kbuf[base];
    float xs[4] = {v.x, v.y, v.z, v.w};
    unsigned short hs[4], ls[4];
#pragma unroll
    for (int i = 0; i < 4; ++i) {
        hs[i] = f2bf(xs[i]);
        ls[i] = f2bf(xs[i] - bf2f(hs[i]));
    }
    uint2 uh; uh.x = (unsigned)hs[0] | ((unsigned)hs[1] << 16);
              uh.y = (unsigned)hs[2] | ((unsigned)hs[3] << 16);
    uint2 ul; ul.x = (unsigned)ls[0] | ((unsigned)ls[1] << 16);
              ul.y = (unsigned)ls[2] | ((unsigned)ls[3] << 16);
    *(uint2*)&Kh[base] = uh;
    *(uint2*)&Kl[base] = ul;
}

// ---------------------------------------------------------------------------
// Q projection via split-bf16 MFMA: q32[row][col] = pack(split(SCALE*(tgt@Wq+bq)))
// Tile 128x128, BK=64, 4 waves. Grid: (nb*16) m-blocks x 8 n-blocks.
// ---------------------------------------------------------------------------
__global__ __launch_bounds__(256, 2) void qproj_kernel(
    const float* __restrict__ tgt,
    const unsigned short* __restrict__ WqTh, const unsigned short* __restrict__ WqTl,
    const float* __restrict__ bq,
    unsigned* __restrict__ q32,
    int row0)
{
    __shared__ __attribute__((aligned(16))) float At[128 * 64];
    __shared__ __attribute__((aligned(16))) unsigned short Bh[128 * 64];
    __shared__ __attribute__((aligned(16))) unsigned short Bl[128 * 64];

    const int t    = threadIdx.x;
    const int lane = t & 63, w = t >> 6;
    const int mb   = blockIdx.x >> 3;
    const int n0   = (blockIdx.x & 7) * 128;

    f32x4 acc[2][8];
#pragma unroll
    for (int m = 0; m < 2; ++m)
#pragma unroll
        for (int n = 0; n < 8; ++n) acc[m][n] = (f32x4){0.f, 0.f, 0.f, 0.f};

    for (int k0 = 0; k0 < D_; k0 += 64) {
        __syncthreads();
#pragma unroll
        for (int it = 0; it < 8; ++it) {      // stage tgt 128x64 f32, swizzled
            int id = it * 256 + t;
            int r = id >> 4, c = id & 15;
            float4 v = *(const float4*)&tgt[(size_t)(row0 + mb * 128 + r) * D_ + k0 + c * 4];
            *(float4*)&At[r * 64 + ((c ^ (r & 15)) << 2)] = v;
        }
#pragma unroll
        for (int it = 0; it < 4; ++it) {      // stage WqT hi/lo 128x64 bf16
            int id = it * 256 + t;
            int r = id >> 3, c = id & 7;
            size_t gofs = (size_t)(n0 + r) * D_ + k0 + c * 8;
            int lofs = r * 64 + ((c ^ (r & 7)) << 3);
            *(uint4*)&Bh[lofs] = *(const uint4*)&WqTh[gofs];
            *(uint4*)&Bl[lofs] = *(const uint4*)&WqTl[gofs];
        }
        __syncthreads();

#pragma unroll
        for (int ki = 0; ki < 2; ++ki) {
            short8 ah[2], al[2];
#pragma unroll
            for (int m = 0; m < 2; ++m) {
                int r = w * 32 + m * 16 + (lane & 15);
                int slot = ki * 8 + ((lane >> 4) << 1);
                float4 x0 = *(const float4*)&At[r * 64 + ((slot ^ (r & 15)) << 2)];
                float4 x1 = *(const float4*)&At[r * 64 + (((slot + 1) ^ (r & 15)) << 2)];
                float xs[8] = {x0.x, x0.y, x0.z, x0.w, x1.x, x1.y, x1.z, x1.w};
#pragma unroll
                for (int j = 0; j < 8; ++j) {
                    unsigned short hh = f2bf(xs[j]);
                    ah[m][j] = (short)hh;
                    al[m][j] = (short)f2bf(xs[j] - bf2f(hh));
                }
            }
#pragma unroll
            for (int n = 0; n < 8; ++n) {
                int nn = n * 16 + (lane & 15);
                int slot = ki * 4 + (lane >> 4);
                int lofs = nn * 64 + ((slot ^ (nn & 7)) << 3);
                short8 bh = *(short8*)&Bh[lofs];
                short8 bl = *(short8*)&Bl[lofs];
#pragma unroll
                for (int m = 0; m < 2; ++m) {
                    acc[m][n] = __builtin_amdgcn_mfma_f32_16x16x32_bf16(ah[m], bh, acc[m][n], 0, 0, 0);
                    acc[m][n] = __builtin_amdgcn_mfma_f32_16x16x32_bf16(ah[m], bl, acc[m][n], 0, 0, 0);
                    acc[m][n] = __builtin_amdgcn_mfma_f32_16x16x32_bf16(al[m], bh, acc[m][n], 0, 0, 0);
                }
            }
        }
    }

#pragma unroll
    for (int n = 0; n < 8; ++n) {
        int col = n0 + n * 16 + (lane & 15);
        float bqv = bq[col];
#pragma unroll
        for (int m = 0; m < 2; ++m) {
            int rbase = mb * 128 + w * 32 + m * 16 + ((lane >> 4) << 2);
#pragma unroll
            for (int r = 0; r < 4; ++r) {
                float q = (acc[m][n][r] + bqv) * SCALE_;
                unsigned short hh = f2bf(q);
                unsigned short ll = f2bf(q - bf2f(hh));
                q32[(size_t)(rbase + r) * D_ + col] = (unsigned)hh | ((unsigned)ll << 16);
            }
        }
    }
}

// ---------------------------------------------------------------------------
// Scores via split-bf16 MFMA, 2-pass (Z then p), tmps accumulation.
// Block: (b, h, 64 l-rows); 4 waves; A-frags hoisted to registers.
// ---------------------------------------------------------------------------
__global__ __launch_bounds__(256, 3) void scores_mfma_kernel(
    const unsigned* __restrict__ q32,
    const unsigned short* __restrict__ Kh, const unsigned short* __restrict__ Kl,
    float* __restrict__ tmps, int b0)
{
    __shared__ __attribute__((aligned(16))) unsigned short SH[64 * 128];
    __shared__ __attribute__((aligned(16))) unsigned short SL[64 * 128];
    __shared__ float tmps_l[1024];

    const int t    = threadIdx.x;
    const int lane = t & 63, w = t >> 6;
    const int blk  = blockIdx.x;
    const int bb   = blk >> 8;
    const int h    = (blk >> 5) & 7;
    const int lt   = blk & 31;
    const int qrow0 = bb * 2048 + lt * 64;
    const int bh    = (b0 + bb) * H_ + h;

    for (int i = t; i < 1024; i += 256) tmps_l[i] = 0.f;

    // stage Q tile (packed hi|lo) -> SH/SL, swizzled
#pragma unroll
    for (int it = 0; it < 8; ++it) {
        int id = it * 256 + t;
        int r = id >> 5, c = id & 31;               // c: 4-col chunk
        uint4 v = *(const uint4*)&q32[(size_t)(qrow0 + r) * D_ + h * E_ + c * 4];
        uint2 uh; uh.x = (v.x & 0xffffu) | ((v.y & 0xffffu) << 16);
                  uh.y = (v.z & 0xffffu) | ((v.w & 0xffffu) << 16);
        uint2 ul; ul.x = (v.x >> 16) | (v.y & 0xffff0000u);
                  ul.y = (v.z >> 16) | (v.w & 0xffff0000u);
        int slot = c >> 1, half = c & 1;
        int lofs = r * 128 + (((slot ^ (r & 15)) << 3) | (half << 2));
        *(uint2*)&SH[lofs] = uh;
        *(uint2*)&SL[lofs] = ul;
    }
    __syncthreads();

    // hoist A-frags (16 q-rows per wave, full E=128)
    short8 qh[4], ql[4];
#pragma unroll
    for (int ki = 0; ki < 4; ++ki) {
        int r = w * 16 + (lane & 15);
        int slot = ki * 4 + (lane >> 4);
        int lofs = r * 128 + ((slot ^ (r & 15)) << 3);
        qh[ki] = *(short8*)&SH[lofs];
        ql[ki] = *(short8*)&SL[lofs];
    }

    float zacc[4] = {0.f, 0.f, 0.f, 0.f};
    float invZ[4];

    for (int pass = 0; pass < 2; ++pass) {
        for (int st = 0; st < 16; ++st) {
            __syncthreads();
#pragma unroll
            for (int it = 0; it < 4; ++it) {        // stage K tile 64x128 hi/lo
                int id = it * 256 + t;
                int r = id >> 4, c = id & 15;
                size_t gofs = (size_t)(st * 64 + r) * D_ + h * E_ + c * 8;
                int lofs = r * 128 + ((c ^ (r & 15)) << 3);
                *(uint4*)&SH[lofs] = *(const uint4*)&Kh[gofs];
                *(uint4*)&SL[lofs] = *(const uint4*)&Kl[gofs];
            }
            __syncthreads();

            f32x4 acc[4];
#pragma unroll
            for (int nf = 0; nf < 4; ++nf) acc[nf] = (f32x4){0.f, 0.f, 0.f, 0.f};
#pragma unroll
            for (int ki = 0; ki < 4; ++ki) {
#pragma unroll
                for (int nf = 0; nf < 4; ++nf) {
                    int sr = nf * 16 + (lane & 15);
                    int slot = ki * 4 + (lane >> 4);
                    int lofs = sr * 128 + ((slot ^ (sr & 15)) << 3);
                    short8 bh = *(short8*)&SH[lofs];
                    short8 bl = *(short8*)&SL[lofs];
                    acc[nf] = __builtin_amdgcn_mfma_f32_16x16x32_bf16(qh[ki], bh, acc[nf], 0, 0, 0);
                    acc[nf] = __builtin_amdgcn_mfma_f32_16x16x32_bf16(qh[ki], bl, acc[nf], 0, 0, 0);
                    acc[nf] = __builtin_amdgcn_mfma_f32_16x16x32_bf16(ql[ki], bh, acc[nf], 0, 0, 0);
                }
            }

            if (pass == 0) {
#pragma unroll
                for (int nf = 0; nf < 4; ++nf) {
                    int s = st * 64 + nf * 16 + (lane & 15);
                    if (s < S_) {
#pragma unroll
                        for (int r = 0; r < 4; ++r) zacc[r] += __expf(acc[nf][r]);
                    }
                }
            } else {
#pragma unroll
                for (int nf = 0; nf < 4; ++nf) {
                    int s = st * 64 + nf * 16 + (lane & 15);
                    if (s < S_) {
                        float p = 0.f;
#pragma unroll
                        for (int r = 0; r < 4; ++r) p += __expf(acc[nf][r]) * invZ[r];
                        atomicAdd(&tmps_l[s], p);
                    }
                }
            }
        }
        if (pass == 0) {
#pragma unroll
            for (int r = 0; r < 4; ++r) {
                float z = zacc[r];
                z += __shfl_xor(z, 1);
                z += __shfl_xor(z, 2);
                z += __shfl_xor(z, 4);
                z += __shfl_xor(z, 8);
                invZ[r] = 1.f / z;
            }
        }
    }

    __syncthreads();
    for (int i = t; i < S_; i += 256)
        atomicAdd(&tmps[(size_t)bh * S_ + i], tmps_l[i]);
}

// ---------------------------------------------------------------------------
// Top-k (round-1, passing)
// ---------------------------------------------------------------------------
__global__ __launch_bounds__(256) void topk_kernel(
    const float* __restrict__ tmps, int* __restrict__ idxs)
{
    const int bh = blockIdx.x;
    const int t  = threadIdx.x;
    __shared__ float v[S_];
    __shared__ float rv[256];
    __shared__ int   ri[256];

    for (int i = t; i < S_; i += 256) v[i] = tmps[(size_t)bh * S_ + i];
    __syncthreads();

    for (int it = 0; it < TOPK_; ++it) {
        float best = -1e38f;
        int bi = 0x7fffffff;
        for (int s = t; s < S_; s += 256) {
            const float x = v[s];
            if (x > best) { best = x; bi = s; }
        }
        rv[t] = best; ri[t] = bi;
        __syncthreads();
        for (int k = 128; k > 0; k >>= 1) {
            if (t < k) {
                const float x = rv[t + k];
                const int  xi = ri[t + k];
                if (x > rv[t] || (x == rv[t] && xi < ri[t])) { rv[t] = x; ri[t] = xi; }
            }
            __syncthreads();
        }
        if (t == 0) {
            idxs[bh * TOPK_ + it] = ri[0];
            v[ri[0]] = -1e38f;
        }
        __syncthreads();
    }
}

// ---------------------------------------------------------------------------
// Gather (round-1, passing)
// ---------------------------------------------------------------------------
__global__ __launch_bounds__(256) void gather_kernel(
    const float* __restrict__ K, const int* __restrict__ idxs,
    float* __restrict__ tok)
{
    const int o = blockIdx.x * 256 + threadIdx.x;
    if (o >= B_ * TOPK_ * D_) return;
    const int d  = o & (D_ - 1);
    const int tt = (o >> 10) % TOPK_;
    const int b  = o / (D_ * TOPK_);
    const int h  = d >> 7;
    const int s  = idxs[(b * H_ + h) * TOPK_ + tt];
    tok[o] = K[(size_t)s * D_ + d];
}

// ---------------------------------------------------------------------------
extern "C" void kernel_launch(void* const* d_in, const int* in_sizes, int n_in,
                              void* d_out, int out_size, void* d_ws, size_t ws_size,
                              hipStream_t stream)
{
    const float* tgt = (const float*)d_in[0];
    const float* src = (const float*)d_in[1];
    const float* Wq  = (const float*)d_in[2];
    const float* bq  = (const float*)d_in[3];
    const float* Wk  = (const float*)d_in[4];
    const float* bk  = (const float*)d_in[5];
    const float* Wo  = (const float*)d_in[6];
    const float* bo  = (const float*)d_in[7];
    float* out = (float*)d_out;

    // workspace layout (bytes, all 256-aligned)
    char* ws = (char*)d_ws;
    size_t off = 0;
    float*          Kbuf = (float*)(ws + off);          off += (size_t)S_ * D_ * 4;            // 4,096,000
    float*          tmps = (float*)(ws + off);          off += (size_t)B_ * H_ * S_ * 4;       //   256,000
    int*            idxs = (int*)(ws + off);            off += (size_t)B_ * H_ * TOPK_ * 4;    //     2,560
    float*          tok  = (float*)(ws + off);          off += (size_t)B_ * TOPK_ * D_ * 4;    //   327,680
    unsigned short* Kh   = (unsigned short*)(ws + off); off += (size_t)1024 * D_ * 2;          // 2,097,152
    unsigned short* Kl   = (unsigned short*)(ws + off); off += (size_t)1024 * D_ * 2;
    unsigned short* WqTh = (unsigned short*)(ws + off); off += (size_t)D_ * D_ * 2;
    unsigned short* WqTl = (unsigned short*)(ws + off); off += (size_t)D_ * D_ * 2;
    unsigned*       q32  = (unsigned*)(ws + off);
    const size_t fixed_bytes = off;
    const size_t q_per_b = (size_t)L_ * D_ * 4;         // 8,388,608 B per batch

    int nb_fit = 1;
    if (ws_size > fixed_bytes) {
        size_t f = (ws_size - fixed_bytes) / q_per_b;
        nb_fit = (f < 1) ? 1 : (f > 8 ? 8 : (int)f);
    }

    hipMemsetAsync(tmps, 0, (size_t)B_ * H_ * S_ * sizeof(float), stream);

    // K = source @ Wk + bk (f32, exact — feeds output via gather)
    {
        dim3 g(D_ / 64, (S_ + 63) / 64);
        gemm_bias_kernel<<<g, 256, 0, stream>>>(src, Wk, bk, Kbuf, S_, D_, D_);
    }
    splitK_kernel<<<(1024 * D_) / (256 * 4), 256, 0, stream>>>(Kbuf, Kh, Kl);
    {
        dim3 g(D_ / 64, D_ / 64);
        splitWqT_kernel<<<g, 256, 0, stream>>>(Wq, WqTh, WqTl);
    }

    for (int b0 = 0; b0 < B_; b0 += nb_fit) {
        int nb = (B_ - b0 < nb_fit) ? (B_ - b0) : nb_fit;
        qproj_kernel<<<nb * 128, 256, 0, stream>>>(tgt, WqTh, WqTl, bq, q32, b0 * L_);
        scores_mfma_kernel<<<nb * 256, 256, 0, stream>>>(q32, Kh, Kl, tmps, b0);
    }

    topk_kernel<<<B_ * H_, 256, 0, stream>>>(tmps, idxs);
    gather_kernel<<<(B_ * TOPK_ * D_ + 255) / 256, 256, 0, stream>>>(Kbuf, idxs, tok);
    {
        dim3 g(D_ / 64, (B_ * TOPK_ + 63) / 64);
        gemm_bias_kernel<<<g, 256, 0, stream>>>(tok, Wo, bo, out, B_ * TOPK_, D_, D_);
    }
}

// Round 4
// 549.711 us; speedup vs baseline: 8.7325x; 1.0765x over previous
//
#include <hip/hip_runtime.h>
#include <hip/hip_bf16.h>
#include <math.h>

// Problem constants
constexpr int B_ = 8;
constexpr int L_ = 2048;
constexpr int S_ = 1000;
constexpr int D_ = 1024;
constexpr int H_ = 8;
constexpr int E_ = 128;     // D/H
constexpr int TOPK_ = 10;
// (1/sqrt(E)) * log2(e): scores in log2 domain so p = exp2(sc)
constexpr float SCALE_LOG2E_ = 0.12751744f;

typedef __attribute__((ext_vector_type(8))) short short8;   // 8 x bf16 (4 VGPRs)
typedef __attribute__((ext_vector_type(4))) float f32x4;

__device__ inline unsigned short f2bf(float x) {            // RTN-even f32->bf16
    unsigned u = __float_as_uint(x);
    unsigned r = (u + 0x7fffu + ((u >> 16) & 1u)) >> 16;
    return (unsigned short)r;
}
__device__ inline float bf2f(unsigned short s) {
    return __uint_as_float(((unsigned)s) << 16);
}

// ---------------------------------------------------------------------------
// Generic f32 GEMM + bias: C[M][N] = A[M][K] @ Bm[K][N] + bias[N]
// (r1-proven; used for K projection [exact path to output] + final GEMM)
// ---------------------------------------------------------------------------
__global__ __launch_bounds__(256) void gemm_bias_kernel(
    const float* __restrict__ A, const float* __restrict__ Bm,
    const float* __restrict__ bias, float* __restrict__ C,
    int M, int N, int Kd)
{
    __shared__ float As[16][65];
    __shared__ float Bs[16][68];

    const int t  = threadIdx.x;
    const int tx = t & 15;
    const int ty = t >> 4;
    const int m0 = blockIdx.y * 64;
    const int n0 = blockIdx.x * 64;

    float acc[4][4];
#pragma unroll
    for (int i = 0; i < 4; ++i)
#pragma unroll
        for (int j = 0; j < 4; ++j) acc[i][j] = 0.f;

    for (int k0 = 0; k0 < Kd; k0 += 16) {
        {
            const int row = t >> 2;
            const int c4  = (t & 3) * 4;
            float4 v = {0.f, 0.f, 0.f, 0.f};
            if (m0 + row < M)
                v = *(const float4*)&A[(size_t)(m0 + row) * Kd + k0 + c4];
            As[c4 + 0][row] = v.x;
            As[c4 + 1][row] = v.y;
            As[c4 + 2][row] = v.z;
            As[c4 + 3][row] = v.w;
        }
        {
            const int row = t >> 4;
            const int c4  = (t & 15) * 4;
            float4 v = *(const float4*)&Bm[(size_t)(k0 + row) * N + n0 + c4];
            *(float4*)&Bs[row][c4] = v;
        }
        __syncthreads();
#pragma unroll
        for (int k = 0; k < 16; ++k) {
            float a[4], b[4];
#pragma unroll
            for (int i = 0; i < 4; ++i) a[i] = As[k][ty * 4 + i];
            float4 bv = *(const float4*)&Bs[k][tx * 4];
            b[0] = bv.x; b[1] = bv.y; b[2] = bv.z; b[3] = bv.w;
#pragma unroll
            for (int i = 0; i < 4; ++i)
#pragma unroll
                for (int j = 0; j < 4; ++j) acc[i][j] += a[i] * b[j];
        }
        __syncthreads();
    }

#pragma unroll
    for (int i = 0; i < 4; ++i) {
        const int row = m0 + ty * 4 + i;
        if (row < M) {
#pragma unroll
            for (int j = 0; j < 4; ++j) {
                const int col = n0 + tx * 4 + j;
                C[(size_t)row * N + col] = acc[i][j] + bias[col];
            }
        }
    }
}

// ---------------------------------------------------------------------------
// WT split (transpose + hi/lo): WTh/WTl[n][k] = split(W[k][n]). (r2-proven)
// ---------------------------------------------------------------------------
__global__ __launch_bounds__(256) void splitWT_kernel(
    const float* __restrict__ W,
    unsigned short* __restrict__ WTh, unsigned short* __restrict__ WTl)
{
    __shared__ __attribute__((aligned(16))) float tile[64][68];
    const int t  = threadIdx.x;
    const int k0 = blockIdx.y * 64, n0 = blockIdx.x * 64;
#pragma unroll
    for (int it = 0; it < 4; ++it) {
        int id = it * 256 + t;
        int r = id >> 4, c = id & 15;
        *(float4*)&tile[r][c * 4] = *(const float4*)&W[(size_t)(k0 + r) * D_ + n0 + c * 4];
    }
    __syncthreads();
#pragma unroll
    for (int it = 0; it < 4; ++it) {
        int id = it * 256 + t;
        int n = id >> 4, c = id & 15;
        unsigned short hs[4], ls[4];
#pragma unroll
        for (int i = 0; i < 4; ++i) {
            float x = tile[c * 4 + i][n];
            hs[i] = f2bf(x);
            ls[i] = f2bf(x - bf2f(hs[i]));
        }
        size_t o = (size_t)(n0 + n) * D_ + k0 + c * 4;
        uint2 uh; uh.x = (unsigned)hs[0] | ((unsigned)hs[1] << 16);
                  uh.y = (unsigned)hs[2] | ((unsigned)hs[3] << 16);
        uint2 ul; ul.x = (unsigned)ls[0] | ((unsigned)ls[1] << 16);
                  ul.y = (unsigned)ls[2] | ((unsigned)ls[3] << 16);
        *(uint2*)&WTh[o] = uh;
        *(uint2*)&WTl[o] = ul;
    }
}

// ---------------------------------------------------------------------------
// K split: Kh/Kl[1024(pad)][1024] bf16 hi/lo; rows >= 1000 zeroed. (r2-proven)
// ---------------------------------------------------------------------------
__global__ __launch_bounds__(256) void splitK_kernel(
    const float* __restrict__ Kbuf,
    unsigned short* __restrict__ Kh, unsigned short* __restrict__ Kl)
{
    int idx  = blockIdx.x * 256 + threadIdx.x;
    int base = idx * 4;
    int row  = base >> 10;
    float4 v = {0.f, 0.f, 0.f, 0.f};
    if (row < S_) v = *(const float4*)&Kbuf[base];
    float xs[4] = {v.x, v.y, v.z, v.w};
    unsigned short hs[4], ls[4];
#pragma unroll
    for (int i = 0; i < 4; ++i) {
        hs[i] = f2bf(xs[i]);
        ls[i] = f2bf(xs[i] - bf2f(hs[i]));
    }
    uint2 uh; uh.x = (unsigned)hs[0] | ((unsigned)hs[1] << 16);
              uh.y = (unsigned)hs[2] | ((unsigned)hs[3] << 16);
    uint2 ul; ul.x = (unsigned)ls[0] | ((unsigned)ls[1] << 16);
              ul.y = (unsigned)ls[2] | ((unsigned)ls[3] << 16);
    *(uint2*)&Kh[base] = uh;
    *(uint2*)&Kl[base] = ul;
}

// ---------------------------------------------------------------------------
// Q projection, 3-term split (ah*bh + ah*bl + al*bh), hi/lo split of tgt done
// at staging time. Output: planar q hi/lo bf16 with SCALE*log2(e) baked in.
// Tile 128x128, BK=64; grid (nb*16) mb x 8 nb.
// ---------------------------------------------------------------------------
__global__ __launch_bounds__(256, 2) void qproj_kernel(
    const float* __restrict__ tgt,   // pre-offset to chunk start
    const unsigned short* __restrict__ WqTh, const unsigned short* __restrict__ WqTl,
    const float* __restrict__ bq,
    unsigned short* __restrict__ qhb, unsigned short* __restrict__ qlb)
{
    __shared__ __attribute__((aligned(16))) unsigned short Ah[128 * 64];
    __shared__ __attribute__((aligned(16))) unsigned short Al[128 * 64];
    __shared__ __attribute__((aligned(16))) unsigned short Bh[128 * 64];
    __shared__ __attribute__((aligned(16))) unsigned short Bl[128 * 64];

    const int t    = threadIdx.x;
    const int lane = t & 63, w = t >> 6;
    const int mb   = blockIdx.x >> 3;
    const int n0   = (blockIdx.x & 7) * 128;

    f32x4 acc[2][8];
#pragma unroll
    for (int m = 0; m < 2; ++m)
#pragma unroll
        for (int n = 0; n < 8; ++n) acc[m][n] = (f32x4){0.f, 0.f, 0.f, 0.f};

    for (int k0 = 0; k0 < D_; k0 += 64) {
        __syncthreads();
#pragma unroll
        for (int it = 0; it < 4; ++it) {
            int id = it * 256 + t;
            int r = id >> 3, c = id & 7;
            int lofs = r * 64 + ((c ^ (r & 7)) << 3);
            // A: load 8 f32 of tgt, split hi/lo at staging time
            const float* ga = &tgt[(size_t)(mb * 128 + r) * D_ + k0 + c * 8];
            float4 v0 = *(const float4*)ga;
            float4 v1 = *(const float4*)(ga + 4);
            float xs[8] = {v0.x, v0.y, v0.z, v0.w, v1.x, v1.y, v1.z, v1.w};
            unsigned short hs[8], ls[8];
#pragma unroll
            for (int j = 0; j < 8; ++j) {
                hs[j] = f2bf(xs[j]);
                ls[j] = f2bf(xs[j] - bf2f(hs[j]));
            }
            uint4 uh, ul;
            uh.x = (unsigned)hs[0] | ((unsigned)hs[1] << 16);
            uh.y = (unsigned)hs[2] | ((unsigned)hs[3] << 16);
            uh.z = (unsigned)hs[4] | ((unsigned)hs[5] << 16);
            uh.w = (unsigned)hs[6] | ((unsigned)hs[7] << 16);
            ul.x = (unsigned)ls[0] | ((unsigned)ls[1] << 16);
            ul.y = (unsigned)ls[2] | ((unsigned)ls[3] << 16);
            ul.z = (unsigned)ls[4] | ((unsigned)ls[5] << 16);
            ul.w = (unsigned)ls[6] | ((unsigned)ls[7] << 16);
            *(uint4*)&Ah[lofs] = uh;
            *(uint4*)&Al[lofs] = ul;
            // B copy (already bf16 hi/lo)
            size_t gb = (size_t)(n0 + r) * D_ + k0 + c * 8;
            *(uint4*)&Bh[lofs] = *(const uint4*)&WqTh[gb];
            *(uint4*)&Bl[lofs] = *(const uint4*)&WqTl[gb];
        }
        __syncthreads();

#pragma unroll
        for (int ki = 0; ki < 2; ++ki) {
            short8 ah[2], al[2];
#pragma unroll
            for (int m = 0; m < 2; ++m) {
                int r = w * 32 + m * 16 + (lane & 15);
                int slot = ki * 4 + (lane >> 4);
                int lofs = r * 64 + ((slot ^ (r & 7)) << 3);
                ah[m] = *(short8*)&Ah[lofs];
                al[m] = *(short8*)&Al[lofs];
            }
#pragma unroll
            for (int n = 0; n < 8; ++n) {
                int nn = n * 16 + (lane & 15);
                int slot = ki * 4 + (lane >> 4);
                int lofs = nn * 64 + ((slot ^ (nn & 7)) << 3);
                short8 bh = *(short8*)&Bh[lofs];
                short8 bl = *(short8*)&Bl[lofs];
#pragma unroll
                for (int m = 0; m < 2; ++m) {
                    acc[m][n] = __builtin_amdgcn_mfma_f32_16x16x32_bf16(ah[m], bh, acc[m][n], 0, 0, 0);
                    acc[m][n] = __builtin_amdgcn_mfma_f32_16x16x32_bf16(ah[m], bl, acc[m][n], 0, 0, 0);
                    acc[m][n] = __builtin_amdgcn_mfma_f32_16x16x32_bf16(al[m], bh, acc[m][n], 0, 0, 0);
                }
            }
        }
    }

#pragma unroll
    for (int n = 0; n < 8; ++n) {
        int col = n0 + n * 16 + (lane & 15);
        float bqv = bq[col];
#pragma unroll
        for (int m = 0; m < 2; ++m) {
            int rbase = mb * 128 + w * 32 + m * 16 + ((lane >> 4) << 2);
#pragma unroll
            for (int r = 0; r < 4; ++r) {
                float q = (acc[m][n][r] + bqv) * SCALE_LOG2E_;
                unsigned short hh = f2bf(q);
                qhb[(size_t)(rbase + r) * D_ + col] = hh;
                qlb[(size_t)(rbase + r) * D_ + col] = f2bf(q - bf2f(hh));
            }
        }
    }
}

// ---------------------------------------------------------------------------
// Scores, 2-pass (Z then normalize), 3-term split — r2-proven numerics with
// 128 q-rows/block (K staging per FLOP halved vs r2). 4 waves, 32 rows/wave
// (2 row-groups); B-fragment reads shared across 6 MFMAs.
// ---------------------------------------------------------------------------
__global__ __launch_bounds__(256, 2) void scores2p_kernel(
    const unsigned short* __restrict__ qhb, const unsigned short* __restrict__ qlb,
    const unsigned short* __restrict__ Kh, const unsigned short* __restrict__ Kl,
    float* __restrict__ tmps, int b0)
{
    __shared__ __attribute__((aligned(16))) unsigned short SH[64 * 128];
    __shared__ __attribute__((aligned(16))) unsigned short SL[64 * 128];
    __shared__ float tmps_l[1024];

    const int t    = threadIdx.x;
    const int lane = t & 63, w = t >> 6;
    const int blk  = blockIdx.x;
    const int bb   = blk >> 7;
    const int h    = (blk >> 4) & 7;
    const int lt   = blk & 15;
    const int qrow0 = bb * L_ + lt * 128;        // chunk-local
    const int bh_i  = (b0 + bb) * H_ + h;

    for (int i = t; i < 1024; i += 256) tmps_l[i] = 0.f;

    // ---- stage Q (128 rows x 128 cols, hi/lo) in two 64-row halves; hoist
    short8 qh[2][4], ql[2][4];
#pragma unroll
    for (int hf = 0; hf < 2; ++hf) {
        __syncthreads();
#pragma unroll
        for (int it = 0; it < 4; ++it) {
            int id = it * 256 + t;
            int r = id >> 4, c = id & 15;
            size_t g = (size_t)(qrow0 + hf * 64 + r) * D_ + h * E_ + c * 8;
            int lofs = r * 128 + ((c ^ (r & 15)) << 3);
            *(uint4*)&SH[lofs] = *(const uint4*)&qhb[g];
            *(uint4*)&SL[lofs] = *(const uint4*)&qlb[g];
        }
        __syncthreads();
        if ((w >> 1) == hf) {
#pragma unroll
            for (int rg = 0; rg < 2; ++rg)
#pragma unroll
                for (int ki = 0; ki < 4; ++ki) {
                    int rq = (w & 1) * 32 + rg * 16 + (lane & 15);
                    int slot = ki * 4 + (lane >> 4);
                    int lofs = rq * 128 + ((slot ^ (rq & 15)) << 3);
                    qh[rg][ki] = *(short8*)&SH[lofs];
                    ql[rg][ki] = *(short8*)&SL[lofs];
                }
        }
    }

    float zacc[2][4];
#pragma unroll
    for (int rg = 0; rg < 2; ++rg)
#pragma unroll
        for (int r = 0; r < 4; ++r) zacc[rg][r] = 0.f;
    float invZ[2][4];

    for (int pass = 0; pass < 2; ++pass) {
        for (int st = 0; st < 16; ++st) {
            __syncthreads();
#pragma unroll
            for (int it = 0; it < 4; ++it) {       // stage K tile 64x128 hi/lo
                int id = it * 256 + t;
                int r = id >> 4, c = id & 15;
                size_t g = (size_t)(st * 64 + r) * D_ + h * E_ + c * 8;
                int lofs = r * 128 + ((c ^ (r & 15)) << 3);
                *(uint4*)&SH[lofs] = *(const uint4*)&Kh[g];
                *(uint4*)&SL[lofs] = *(const uint4*)&Kl[g];
            }
            __syncthreads();

            f32x4 acc[2][4];
#pragma unroll
            for (int rg = 0; rg < 2; ++rg)
#pragma unroll
                for (int nf = 0; nf < 4; ++nf) acc[rg][nf] = (f32x4){0.f, 0.f, 0.f, 0.f};

#pragma unroll
            for (int ki = 0; ki < 4; ++ki)
#pragma unroll
                for (int nf = 0; nf < 4; ++nf) {
                    int sr = nf * 16 + (lane & 15);
                    int slot = ki * 4 + (lane >> 4);
                    int lofs = sr * 128 + ((slot ^ (sr & 15)) << 3);
                    short8 bh = *(short8*)&SH[lofs];
                    short8 bl = *(short8*)&SL[lofs];
#pragma unroll
                    for (int rg = 0; rg < 2; ++rg) {
                        acc[rg][nf] = __builtin_amdgcn_mfma_f32_16x16x32_bf16(qh[rg][ki], bh, acc[rg][nf], 0, 0, 0);
                        acc[rg][nf] = __builtin_amdgcn_mfma_f32_16x16x32_bf16(qh[rg][ki], bl, acc[rg][nf], 0, 0, 0);
                        acc[rg][nf] = __builtin_amdgcn_mfma_f32_16x16x32_bf16(ql[rg][ki], bh, acc[rg][nf], 0, 0, 0);
                    }
                }

            if (pass == 0) {
#pragma unroll
                for (int nf = 0; nf < 4; ++nf) {
                    int s = st * 64 + nf * 16 + (lane & 15);
                    if (s < S_) {
#pragma unroll
                        for (int rg = 0; rg < 2; ++rg)
#pragma unroll
                            for (int r = 0; r < 4; ++r)
                                zacc[rg][r] += exp2f(acc[rg][nf][r]);
                    }
                }
            } else {
#pragma unroll
                for (int nf = 0; nf < 4; ++nf) {
                    int s = st * 64 + nf * 16 + (lane & 15);
                    if (s < S_) {
                        float val = 0.f;
#pragma unroll
                        for (int rg = 0; rg < 2; ++rg)
#pragma unroll
                            for (int r = 0; r < 4; ++r)
                                val += exp2f(acc[rg][nf][r]) * invZ[rg][r];
                        atomicAdd(&tmps_l[s], val);
                    }
                }
            }
        }
        if (pass == 0) {
#pragma unroll
            for (int rg = 0; rg < 2; ++rg)
#pragma unroll
                for (int r = 0; r < 4; ++r) {
                    float z = zacc[rg][r];
                    z += __shfl_xor(z, 1);
                    z += __shfl_xor(z, 2);
                    z += __shfl_xor(z, 4);
                    z += __shfl_xor(z, 8);
                    invZ[rg][r] = 1.f / z;
                }
        }
    }

    __syncthreads();
    for (int i = t; i < S_; i += 256)
        atomicAdd(&tmps[(size_t)bh_i * S_ + i], tmps_l[i]);
}

// ---------------------------------------------------------------------------
// Top-k (k=10) per (b,h); ties -> smaller index (matches jax.lax.top_k).
// ---------------------------------------------------------------------------
__global__ __launch_bounds__(256) void topk_kernel(
    const float* __restrict__ tmps, int* __restrict__ idxs)
{
    const int bh = blockIdx.x;
    const int t  = threadIdx.x;
    __shared__ float v[S_];
    __shared__ float rv[256];
    __shared__ int   ri[256];

    for (int i = t; i < S_; i += 256) v[i] = tmps[(size_t)bh * S_ + i];
    __syncthreads();

    for (int it = 0; it < TOPK_; ++it) {
        float best = -1e38f;
        int bi = 0x7fffffff;
        for (int s = t; s < S_; s += 256) {
            const float x = v[s];
            if (x > best) { best = x; bi = s; }
        }
        rv[t] = best; ri[t] = bi;
        __syncthreads();
        for (int k = 128; k > 0; k >>= 1) {
            if (t < k) {
                const float x = rv[t + k];
                const int  xi = ri[t + k];
                if (x > rv[t] || (x == rv[t] && xi < ri[t])) { rv[t] = x; ri[t] = xi; }
            }
            __syncthreads();
        }
        if (t == 0) {
            idxs[bh * TOPK_ + it] = ri[0];
            v[ri[0]] = -1e38f;
        }
        __syncthreads();
    }
}

// ---------------------------------------------------------------------------
// Gather selected K rows into tok[b][topk][D]
// ---------------------------------------------------------------------------
__global__ __launch_bounds__(256) void gather_kernel(
    const float* __restrict__ K, const int* __restrict__ idxs,
    float* __restrict__ tok)
{
    const int o = blockIdx.x * 256 + threadIdx.x;
    if (o >= B_ * TOPK_ * D_) return;
    const int d  = o & (D_ - 1);
    const int tt = (o >> 10) % TOPK_;
    const int b  = o / (D_ * TOPK_);
    const int h  = d >> 7;
    const int s  = idxs[(b * H_ + h) * TOPK_ + tt];
    tok[o] = K[(size_t)s * D_ + d];
}

// ---------------------------------------------------------------------------
extern "C" void kernel_launch(void* const* d_in, const int* in_sizes, int n_in,
                              void* d_out, int out_size, void* d_ws, size_t ws_size,
                              hipStream_t stream)
{
    const float* tgt = (const float*)d_in[0];
    const float* src = (const float*)d_in[1];
    const float* Wq  = (const float*)d_in[2];
    const float* bq  = (const float*)d_in[3];
    const float* Wk  = (const float*)d_in[4];
    const float* bk  = (const float*)d_in[5];
    const float* Wo  = (const float*)d_in[6];
    const float* bo  = (const float*)d_in[7];
    float* out = (float*)d_out;

    // workspace layout (bytes, all 256-aligned)
    char* ws = (char*)d_ws;
    size_t off = 0;
    float*          Kbuf = (float*)(ws + off);          off += (size_t)S_ * D_ * 4;          // 4,096,000
    float*          tmps = (float*)(ws + off);          off += (size_t)B_ * H_ * S_ * 4;     //   256,000
    int*            idxs = (int*)(ws + off);            off += (size_t)B_ * H_ * TOPK_ * 4;  //     2,560 (+pad)
    off = (off + 255) & ~(size_t)255;
    float*          tok  = (float*)(ws + off);          off += (size_t)B_ * TOPK_ * D_ * 4;  //   327,680
    unsigned short* Kh   = (unsigned short*)(ws + off); off += (size_t)1024 * D_ * 2;        // 2 MB
    unsigned short* Kl   = (unsigned short*)(ws + off); off += (size_t)1024 * D_ * 2;        // 2 MB
    unsigned short* WqTh = (unsigned short*)(ws + off); off += (size_t)D_ * D_ * 2;          // 2 MB
    unsigned short* WqTl = (unsigned short*)(ws + off); off += (size_t)D_ * D_ * 2;          // 2 MB
    unsigned short* qhb  = (unsigned short*)(ws + off);
    const size_t fixed_bytes = off;
    // per-batch: q hi plane + q lo plane, 4 MB each
    const size_t q_plane_b = (size_t)L_ * D_ * 2;

    int nb_fit = 1;
    if (ws_size > fixed_bytes) {
        size_t f = (ws_size - fixed_bytes) / (2 * q_plane_b);
        nb_fit = (f < 1) ? 1 : (f > 8 ? 8 : (int)f);
    }

    hipMemsetAsync(tmps, 0, (size_t)B_ * H_ * S_ * sizeof(float), stream);

    // K = src @ Wk + bk (f32 exact, r1-proven) + bf16 hi/lo split (r2-proven)
    {
        dim3 g(D_ / 64, (S_ + 63) / 64);
        gemm_bias_kernel<<<g, 256, 0, stream>>>(src, Wk, bk, Kbuf, S_, D_, D_);
    }
    splitK_kernel<<<(1024 * D_) / (256 * 4), 256, 0, stream>>>(Kbuf, Kh, Kl);
    {
        dim3 g(D_ / 64, D_ / 64);
        splitWT_kernel<<<g, 256, 0, stream>>>(Wq, WqTh, WqTl);
    }

    for (int b0 = 0; b0 < B_; b0 += nb_fit) {
        int nb = (B_ - b0 < nb_fit) ? (B_ - b0) : nb_fit;
        unsigned short* qlb = qhb + (size_t)nb_fit * q_plane_b / 2; // lo plane after hi plane(s)
        qproj_kernel<<<nb * 128, 256, 0, stream>>>(
            tgt + (size_t)b0 * L_ * D_, WqTh, WqTl, bq, qhb, qlb);
        scores2p_kernel<<<nb * 128, 256, 0, stream>>>(qhb, qlb, Kh, Kl, tmps, b0);
    }

    topk_kernel<<<B_ * H_, 256, 0, stream>>>(tmps, idxs);
    gather_kernel<<<(B_ * TOPK_ * D_ + 255) / 256, 256, 0, stream>>>(Kbuf, idxs, tok);
    {
        dim3 g(D_ / 64, (B_ * TOPK_ + 63) / 64);
        gemm_bias_kernel<<<g, 256, 0, stream>>>(tok, Wo, bo, out, B_ * TOPK_, D_, D_);
    }
}